// Round 10
// baseline (2229.670 us; speedup 1.0000x reference)
//
#include <hip/hip_runtime.h>
#include <stdint.h>

typedef unsigned int u32;
typedef unsigned short u16;
typedef __attribute__((ext_vector_type(8))) short bf16x8;    // 8 bf16 = 4 VGPRs
typedef __attribute__((ext_vector_type(4))) float f32x4;     // 16x16 C/D frag
typedef __attribute__((ext_vector_type(16))) float f32x16;   // 32x32 C/D frag
typedef __attribute__((ext_vector_type(4))) u32 u32x4;

#define B_ 4
#define S_ 4096
#define D_ 512
#define SCALE_ 0.04419417382415922f   // 512^-0.5

// ---------- helpers ----------
__device__ __forceinline__ u16 f2b(float f) {               // fp32 -> bf16 RNE (exact)
  u32 u = __builtin_bit_cast(u32, f);
  return (u16)((u + 0x7FFFu + ((u >> 16) & 1u)) >> 16);
}
// async global->LDS, 16B/lane, dst = lds + lane*16 (wave-uniform lds base)
__device__ __forceinline__ void gld16(const void* g, void* l) {
  __builtin_amdgcn_global_load_lds(
      (const __attribute__((address_space(1))) u32*)g,
      (__attribute__((address_space(3))) u32*)l, 16, 0, 0);
}
// v_cvt_pk_bf16_f32: dst.lo16 = bf16(a), dst.hi16 = bf16(b)
__device__ __forceinline__ u32 cvtpk(float a, float b) {
  u32 d;
  asm volatile("v_cvt_pk_bf16_f32 %0, %1, %2" : "=v"(d) : "v"(a), "v"(b));
  return d;
}
// v_permlane32_swap_b32 dst, src: dst lanes 32-63 <-> src lanes 0-31
// (dst-hi <-> src-lo; LLVM gfx950 semantics, matches HK usage)
__device__ __forceinline__ void plswap(u32& dst, u32& src) {
  asm volatile("v_permlane32_swap_b32 %0, %1" : "+v"(dst), "+v"(src));
}

// =====================================================================
// Kernel 0: Wb = bf16(W), one pass. 256x256 threads, 4 elems/thread.
// =====================================================================
__global__ __launch_bounds__(256, 1) void qprep(
    const float* __restrict__ W, u16* __restrict__ Wb) {
  int i = (blockIdx.x * 256 + threadIdx.x) * 4;
  float4 a = *(const float4*)(W + i);
  ushort4 o;
  o.x = f2b(a.x); o.y = f2b(a.y); o.z = f2b(a.z); o.w = f2b(a.w);
  *(ushort4*)(Wb + i) = o;
}

// =====================================================================
// Kernel 1: Q = X @ W^T (NT gemm, bf16 MFMA), writes Qrow [B*S][D] bf16
// and Qt [B][D][S] bf16. (unchanged from the verified version)
// =====================================================================
__global__ __launch_bounds__(256, 1) void qproj(
    const float* __restrict__ X, const u16* __restrict__ Wb,
    u16* __restrict__ Qr, u16* __restrict__ Qt) {
  __shared__ __align__(16) u16 Wt[2][512 * 64];              // 2 x 64 KB
  const int tid = threadIdx.x;
  const int wave = tid >> 6, lane = tid & 63;
  const int m16 = lane & 15, quad = lane >> 4;
  const int r0 = blockIdx.x * 64;

  const float* xrow = X + (size_t)(r0 + wave * 16 + m16) * D_;
  bf16x8 af[16];
#pragma unroll
  for (int ks = 0; ks < 16; ++ks) {
    const float* ap = xrow + ks * 32 + quad * 8;
    float4 a0 = ((const float4*)ap)[0];
    float4 a1 = ((const float4*)ap)[1];
    bf16x8 v;
    v[0] = (short)f2b(a0.x); v[1] = (short)f2b(a0.y);
    v[2] = (short)f2b(a0.z); v[3] = (short)f2b(a0.w);
    v[4] = (short)f2b(a1.x); v[5] = (short)f2b(a1.y);
    v[6] = (short)f2b(a1.z); v[7] = (short)f2b(a1.w);
    af[ks] = v;
  }

  f32x4 acc[32];
#pragma unroll
  for (int i = 0; i < 32; ++i) acc[i] = f32x4{};

  auto stage = [&](int kc, int buf) {
#pragma unroll
    for (int t = 0; t < 16; ++t) {
      int e0 = (wave * 16 + t) * 8;
      int e = e0 + (lane >> 3);
      int gb = ((lane & 7) - e) & 7;
      gld16(Wb + (size_t)e * D_ + kc * 64 + gb * 8, &Wt[buf][e0 * 64]);
    }
  };

  stage(0, 0);
  __syncthreads();

  for (int kc = 0; kc < 8; ++kc) {
    if (kc < 7) stage(kc + 1, (kc + 1) & 1);
    const u16* wb = &Wt[kc & 1][0];
#pragma unroll
    for (int kk = 0; kk < 2; ++kk) {
      int jb = quad + 4 * kk;
      bf16x8 a = af[kc * 2 + kk];
#pragma unroll
      for (int nt = 0; nt < 32; ++nt) {
        int e = m16 + nt * 16;
        bf16x8 bf = *(const bf16x8*)(wb + e * 64 + ((jb + e) & 7) * 8);
        acc[nt] = __builtin_amdgcn_mfma_f32_16x16x32_bf16(a, bf, acc[nt], 0, 0, 0);
      }
    }
    __syncthreads();
  }

  const int b = r0 >> 12;
  const int s0 = (r0 & (S_ - 1)) + wave * 16 + quad * 4;
  const int grow = r0 + wave * 16 + quad * 4;
#pragma unroll
  for (int nt = 0; nt < 32; ++nt) {
    int e = nt * 16 + m16;
    u16 h0 = f2b(acc[nt][0]), h1 = f2b(acc[nt][1]);
    u16 h2 = f2b(acc[nt][2]), h3 = f2b(acc[nt][3]);
    Qr[(size_t)(grow + 0) * D_ + e] = h0;
    Qr[(size_t)(grow + 1) * D_ + e] = h1;
    Qr[(size_t)(grow + 2) * D_ + e] = h2;
    Qr[(size_t)(grow + 3) * D_ + e] = h3;
    uint2 pv;
    pv.x = (u32)h0 | ((u32)h1 << 16);
    pv.y = (u32)h2 | ((u32)h3 << 16);
    *(uint2*)(&Qt[((size_t)(b * D_ + e)) * S_ + s0]) = pv;
  }
}

// =====================================================================
// Kernel 2: flash attention v10 — 32x32x16 MFMA + swapped QK^T (T12).
// v9 with the permlane32_swap ARGUMENT ORDER fixed: HW swaps dst-hi
// with src-lo, so dst must be the LOW-key word, src the HIGH-key word.
// (v9's reversed order permuted P across keys: row-sums stayed exact —
// normalization correct — but PV mixed keys -> absmax 8.77.)
// 256 blocks (64 q-rows each), 2 waves x 32 rows, 64-key tiles.
// Swapped S^T = mfma(K, Q): lane owns q-row -> softmax reg-local;
// P packed in-register via cvt_pk + permlane32_swap (no P LDS trip).
// LDS = Kt 64K + Vt 64K = 128 KB; 2 waves/block, 1 block/CU.
// =====================================================================
__global__ __launch_bounds__(128, 1) void flashattn(
    const u16* __restrict__ Qrow, const u16* __restrict__ Qt,
    float* __restrict__ Out) {
  __shared__ __align__(16) u16 Kt[64 * 512];      // [key n][d], mod-8 rotated slots
  __shared__ __align__(16) u16 Vt[512 * 64];      // [d][key], mod-8 rotated slots

  const int tid = threadIdx.x;
  const int wave = tid >> 6, lane = tid & 63;
  const int l31 = lane & 31, hi = lane >> 5;
  const int qt = blockIdx.x, bb = blockIdx.y;
  const u16* Qb  = Qrow + (size_t)bb * S_ * D_;
  const u16* Qtb = Qt   + (size_t)bb * D_ * S_;

  auto stageK = [&](int kt) {       // 64 key rows x 1KB; 32 instrs per wave
    const u16* src = Qb + (size_t)(kt * 64) * D_;
#pragma unroll
    for (int t = 0; t < 32; ++t) {
      int n = wave * 32 + t;
      int gb = (lane & ~7) | ((lane + n) & 7);
      gld16(src + (size_t)n * D_ + gb * 8, &Kt[n * 512]);
    }
  };
  auto stageV = [&](int kt) {       // 512 d-rows x 128B; 32 instrs per wave
    const u16* vsrc = Qtb + kt * 64;
#pragma unroll
    for (int t = 0; t < 32; ++t) {
      int d0 = (wave * 32 + t) * 8;
      int d  = d0 + (lane >> 3);
      int gb = ((lane & 7) + d) & 7;
      gld16(vsrc + (size_t)d * S_ + gb * 8, &Vt[d0 * 64]);
    }
  };

  stageK(0);                        // DMA overlaps the qf register loads

  // Q B-fragments (swapped: Q is the B operand): lane holds
  // Q[qrow = l31][ks*16 + hi*8 + j]; qrow = qt*64 + wave*32 + l31.
  bf16x8 qf[32];
  {
    const u16* qp = Qb + (size_t)(qt * 64 + wave * 32 + l31) * D_ + hi * 8;
#pragma unroll
    for (int ks = 0; ks < 32; ++ks) qf[ks] = *(const bf16x8*)(qp + ks * 16);
  }

  bf16x8 onesf;                     // constant B-frag of 1.0 for the l-columns
#pragma unroll
  for (int j = 0; j < 8; ++j) onesf[j] = (short)0x3F80;

  f32x16 o[16];
#pragma unroll
  for (int i = 0; i < 16; ++i) o[i] = f32x16{};
  f32x16 ol = f32x16{};             // row-sums of P (C-layout, all cols equal)
  float mrow = -1e30f;              // per-lane running max (lane owns qrow l31)

  __syncthreads();                  // drains K[0]

  for (int kt = 0; kt < 64; ++kt) {
    // ======== phase A: V[kt] streams while S^T = K Q computes ========
    stageV(kt);

    f32x16 s0 = f32x16{}, s1 = f32x16{};
    {
      const u16* k0 = &Kt[(size_t)l31 * 512];          // key group 0 row
      const u16* k1 = &Kt[(size_t)(32 + l31) * 512];   // key group 1 row
      const int n0 = l31, n1 = 32 + l31;
#pragma unroll
      for (int ks = 0; ks < 32; ++ks) {
        int g = 2 * ks + hi;                           // global 16B d-block
        bf16x8 a0 = *(const bf16x8*)(k0 + ((g & ~7) | ((g - n0) & 7)) * 8);
        bf16x8 a1 = *(const bf16x8*)(k1 + ((g & ~7) | ((g - n1) & 7)) * 8);
        s0 = __builtin_amdgcn_mfma_f32_32x32x16_bf16(a0, qf[ks], s0, 0, 0, 0);
        s1 = __builtin_amdgcn_mfma_f32_32x32x16_bf16(a1, qf[ks], s1, 0, 0, 0);
      }
    }

    __syncthreads();                // drains V[kt]; all waves done reading Kt

    // ======== phase B: K[kt+1] streams; softmax + pack + PV ========
    if (kt < 63) stageK(kt + 1);

    // per-lane softmax over the 32 regs (lane = one q-row), + partner half
    float t = s0[0];
#pragma unroll
    for (int r = 1; r < 16; ++r) t = fmaxf(t, s0[r]);
#pragma unroll
    for (int r = 0; r < 16; ++r) t = fmaxf(t, s1[r]);
    t = fmaxf(t, __shfl_xor(t, 32));
    float mn = fmaxf(mrow, t);
    bool grew = mn > mrow;
    float alpha = __expf((mrow - mn) * SCALE_);
    mrow = mn;
#pragma unroll
    for (int r = 0; r < 16; ++r) s0[r] = __expf((s0[r] - mn) * SCALE_);
#pragma unroll
    for (int r = 0; r < 16; ++r) s1[r] = __expf((s1[r] - mn) * SCALE_);

    if (__ballot(grew) != 0ull) {   // rescale O/ol (C-layout rows need bcast)
      float ar[16];
#pragma unroll
      for (int r = 0; r < 16; ++r)
        ar[r] = __shfl(alpha, ((r & 3) + 8 * (r >> 2)) + 4 * hi);
#pragma unroll
      for (int dt = 0; dt < 16; ++dt)
#pragma unroll
        for (int r = 0; r < 16; ++r) o[dt][r] *= ar[r];
#pragma unroll
      for (int r = 0; r < 16; ++r) ol[r] *= ar[r];
    }

    // pack P -> 4 A-frags (keys 0-15,16-31,32-47,48-63) via cvt_pk+permlane.
    // S^T C-layout: reg r of group g holds key g*32 + (r&3)+8*(r>>2)+4*hi,
    // col (q-row) = l31. plswap(dst=LOW-key word, src=HIGH-key word):
    // dst-hi <- src-lo, src-lo <- dst-hi. E.g. x0={0,1}h0/{4,5}h1,
    // y0={8,9}h0/{12,13}h1 -> x0'={0,1}h0/{8,9}h1 = frag word0,
    // y0'={4,5}h0/{12,13}h1 = frag word2.
    bf16x8 pa[4];
    {
      u32 x0, x1, y0, y1; u32x4 f;
      x0 = cvtpk(s0[0], s0[1]);  x1 = cvtpk(s0[2], s0[3]);
      y0 = cvtpk(s0[4], s0[5]);  y1 = cvtpk(s0[6], s0[7]);
      plswap(x0, y0); plswap(x1, y1);
      f[0] = x0; f[1] = x1; f[2] = y0; f[3] = y1;
      pa[0] = __builtin_bit_cast(bf16x8, f);
      x0 = cvtpk(s0[8], s0[9]);  x1 = cvtpk(s0[10], s0[11]);
      y0 = cvtpk(s0[12], s0[13]); y1 = cvtpk(s0[14], s0[15]);
      plswap(x0, y0); plswap(x1, y1);
      f[0] = x0; f[1] = x1; f[2] = y0; f[3] = y1;
      pa[1] = __builtin_bit_cast(bf16x8, f);
      x0 = cvtpk(s1[0], s1[1]);  x1 = cvtpk(s1[2], s1[3]);
      y0 = cvtpk(s1[4], s1[5]);  y1 = cvtpk(s1[6], s1[7]);
      plswap(x0, y0); plswap(x1, y1);
      f[0] = x0; f[1] = x1; f[2] = y0; f[3] = y1;
      pa[2] = __builtin_bit_cast(bf16x8, f);
      x0 = cvtpk(s1[8], s1[9]);  x1 = cvtpk(s1[10], s1[11]);
      y0 = cvtpk(s1[12], s1[13]); y1 = cvtpk(s1[14], s1[15]);
      plswap(x0, y0); plswap(x1, y1);
      f[0] = x0; f[1] = x1; f[2] = y0; f[3] = y1;
      pa[3] = __builtin_bit_cast(bf16x8, f);
    }

    // PV: O[qrow][d] += P(32q x 16k-slice) * V(16k x 32d-tile)
#pragma unroll
    for (int ks2 = 0; ks2 < 4; ++ks2) {
      bf16x8 pf = pa[ks2];
#pragma unroll
      for (int dt = 0; dt < 16; ++dt) {
        int d = dt * 32 + l31;
        int g = 2 * ks2 + hi;                     // global key 16B-block 0..7
        bf16x8 vf = *(const bf16x8*)(&Vt[d * 64 + (((g - d) & 7)) * 8]);
        o[dt] = __builtin_amdgcn_mfma_f32_32x32x16_bf16(pf, vf, o[dt], 0, 0, 0);
      }
      ol = __builtin_amdgcn_mfma_f32_32x32x16_bf16(pf, onesf, ol, 0, 0, 0);
    }

    __syncthreads();                // drains K[kt+1]; Kt/Vt safe for next iter
  }

  // ---- epilogue: y = O / l (both in C-layout; no shuffles needed)
  float inv[16];
#pragma unroll
  for (int r = 0; r < 16; ++r) inv[r] = 1.f / ol[r];
  const int row0 = qt * 64 + wave * 32 + 4 * hi;
#pragma unroll
  for (int dt = 0; dt < 16; ++dt) {
    int col = dt * 32 + l31;
#pragma unroll
    for (int r = 0; r < 16; ++r) {
      int row = row0 + (r & 3) + 8 * (r >> 2);
      Out[((size_t)bb * S_ + row) * D_ + col] = o[dt][r] * inv[r];
    }
  }
}

// =====================================================================
extern "C" void kernel_launch(void* const* d_in, const int* in_sizes, int n_in,
                              void* d_out, int out_size, void* d_ws, size_t ws_size,
                              hipStream_t stream) {
  (void)in_sizes; (void)n_in; (void)out_size; (void)ws_size;
  const float* X = (const float*)d_in[0];
  const float* W = (const float*)d_in[1];
  float* Out = (float*)d_out;
  u16* Qr = (u16*)d_ws;                                   // [B*S][D] bf16, 16.8 MB
  u16* Qt = Qr + (size_t)B_ * S_ * D_;                    // [B][D][S] bf16, 16.8 MB
  u16* Wb = Qt + (size_t)B_ * D_ * S_;                    // [D][D]    bf16, 0.5 MB

  qprep<<<dim3(256), dim3(256), 0, stream>>>(W, Wb);
  qproj<<<dim3(256), dim3(256), 0, stream>>>(X, Wb, Qr, Qt);
  flashattn<<<dim3(64, 4), dim3(128), 0, stream>>>(Qr, Qt, Out);
}